// Round 7
// baseline (15753.522 us; speedup 1.0000x reference)
//
#include <hip/hip_runtime.h>
#include <math.h>

#define Bsz 32
#define Lsz 2048
#define NT  576   // 9 waves: wave 0 = serial chain, waves 1..8 = einsum (512 thr x 4 outputs)

// ---------------- LDS layout (float offsets) ----------------
#define O_Wx1T  0        // [128][20] = 2560  (cols 0..17 real, 18..19 zero; stride 20 = natural bank stagger)
#define O_Wh1T  2560     // [128][32] = 4096  (XOR-swizzled rows)
#define O_Wx2T  6656     // [128][32] = 4096
#define O_Wh2T  10752    // [128][32] = 4096
#define O_Wd1T  14848    // [64][32]  = 2048  (col 31 zero)
#define O_Wd2T  16896    // [64][64]  = 4096
#define O_WfT   20992    // [32][32]  = 1024  (Wf = Wo@Wlin, transposed)
#define O_Mu    22016    // [17][36]  = 616
#define O_B1    22632    // 128
#define O_B2    22760    // 128
#define O_Bd1   22888    // 64
#define O_Bd2   22952    // 64
#define O_Bf    23016    // 32  (bo@Wlin + blin)
#define O_NsT   23048    // [32][66] = 2112  (nsT[d][c])
#define O_State 25160    // 32
#define O_H1    25192    // 32
#define O_H2    25224    // 32
#define O_Inp   25256    // 24 (18 used; 18..19 zero for packed z1 read)
#define O_Co    25280    // 32
#define O_D1    25312    // 64
#define O_Gate  25376    // 64
#define O_Err   25440    // 4
#define O_X     25444    // 2048
#define O_Y     27492    // 2048
#define O_Pred  29540    // 2048
#define SMEM_FLOATS 31588

// XOR swizzle: row j, element k -> float offset within row
#define SW32(j,k) (((((k) >> 2) ^ ((j) & 7)) << 2) | ((k) & 3))
#define SW64(j,k) (((((k) >> 2) ^ ((j) & 7)) << 2) | ((k) & 3))

__device__ __forceinline__ float sigf(float v) {
    return 1.0f / (1.0f + __expf(-v));
}
__device__ __forceinline__ float ftanh(float v) {
    float e = __expf(2.0f * v);
    return 1.0f - 2.0f / (e + 1.0f);
}
__device__ __forceinline__ float dot4(float4 a, float4 b) {
    return a.x*b.x + a.y*b.y + a.z*b.z + a.w*b.w;
}
// swizzled float4 load: row `row`, 4-float block g, row width W floats
__device__ __forceinline__ float4 ldsw(const float* p, int row, int g, int W) {
    return *(const float4*)(p + row * W + (((g ^ (row & 7)) << 2)));
}
#define WFENCE() do { __builtin_amdgcn_wave_barrier(); } while (0)

// 2nd arg = min waves per EU(SIMD): 3 -> VGPR cap 512/3 = 170.
// Round-1/6 evidence: allocator allocates exactly to the cap (128@(512,2), 84@default)
// and spills the einsum's 128-float Wc slice to scratch. 170 fits the ~145 live set.
extern "C" __global__ __launch_bounds__(NT, 3)
void dnc_kernel(const float* __restrict__ x,   const float* __restrict__ y,
                const float* __restrict__ s0,  const float* __restrict__ err0,
                const float* __restrict__ gate0,
                const float* __restrict__ Wc,  const float* __restrict__ Ux,
                const float* __restrict__ bc,  const float* __restrict__ mu,
                const float* __restrict__ Wx1, const float* __restrict__ Wh1,
                const float* __restrict__ b1,
                const float* __restrict__ Wx2, const float* __restrict__ Wh2,
                const float* __restrict__ b2,
                const float* __restrict__ Wo,  const float* __restrict__ bo,
                const float* __restrict__ Wlin,const float* __restrict__ blin,
                const float* __restrict__ Wd1, const float* __restrict__ bd1,
                const float* __restrict__ Wd2, const float* __restrict__ bd2,
                float* __restrict__ out)
{
    extern __shared__ float sm[];
    const int tid = threadIdx.x;
    const int b   = blockIdx.x;

    // ---------------- prologue: stage transposed/swizzled weights ----------------
    for (int i = tid; i < 128*20; i += NT) { int j = i / 20, k = i % 20;
        sm[O_Wx1T + i] = (k < 18) ? Wx1[k*128 + j] : 0.0f; }
    for (int i = tid; i < 4096; i += NT) { int j = i & 127, k = i >> 7;
        sm[O_Wh1T + j*32 + SW32(j,k)] = Wh1[k*128 + j]; }
    for (int i = tid; i < 4096; i += NT) { int j = i & 127, k = i >> 7;
        sm[O_Wx2T + j*32 + SW32(j,k)] = Wx2[k*128 + j]; }
    for (int i = tid; i < 4096; i += NT) { int j = i & 127, k = i >> 7;
        sm[O_Wh2T + j*32 + SW32(j,k)] = Wh2[k*128 + j]; }
    for (int i = tid; i < 2048; i += NT) { int j = i & 63, k = i >> 6;
        sm[O_Wd1T + j*32 + SW32(j,k)] = (k < 31) ? Wd1[k*64 + j] : 0.0f; }
    for (int i = tid; i < 4096; i += NT) { int j = i & 63, k = i >> 6;
        sm[O_Wd2T + j*64 + SW64(j,k)] = Wd2[k*64 + j]; }
    for (int i = tid; i < 1024; i += NT) { int j = i & 31, k = i >> 5;
        float a = 0.0f;
        for (int m = 0; m < 18; ++m) a += Wo[k*18 + m] * Wlin[m*32 + j];
        sm[O_WfT + j*32 + SW32(j,k)] = a; }
    for (int i = tid; i < 17*32; i += NT) { int r = i >> 5, s2 = i & 31;
        sm[O_Mu + r*36 + s2] = mu[i]; }
    if (tid < 128) { sm[O_B1 + tid] = b1[tid]; sm[O_B2 + tid] = b2[tid]; }
    if (tid < 64)  { sm[O_Bd1 + tid] = bd1[tid]; sm[O_Bd2 + tid] = bd2[tid]; }
    if (tid < 32)  {
        float a = blin[tid];
        for (int m = 0; m < 18; ++m) a += bo[m] * Wlin[m*32 + tid];
        sm[O_Bf + tid] = a;
        sm[O_State + tid] = s0[tid];
        sm[O_H1 + tid] = 0.0f; sm[O_H2 + tid] = 0.0f;
    }
    if (tid >= 18 && tid < 24) sm[O_Inp + tid] = 0.0f;
    if (tid == 0) sm[O_Err] = err0[b];
    for (int i = tid; i < Lsz; i += NT) sm[O_X + i] = x[b*Lsz + i];
    for (int i = tid; i < Lsz; i += NT) sm[O_Y + i] = y[b*Lsz + i];

    // ---------------- per-branch register state ----------------
    // einsum threads (tid>=64): e in [0,512), outputs o = e + 512k, k=0..3
    //   d = e&31 (same for all k), c = (e>>5) + 16k
    const int e = tid - 64;
    float wc0[32], wc1[32], wc2[32], wc3[32];
    float u0, u1, u2, u3, bb0, bb1, bb2, bb3;
    float c1 = 0.0f, c2 = 0.0f, gate_reg = 0.0f;

    if (tid >= 64) {
        const int d  = e & 31;
        const int cb = e >> 5;
        #pragma unroll
        for (int s = 0; s < 32; ++s) {
            wc0[s] = Wc[(cb      )*1024 + s*32 + d];
            wc1[s] = Wc[(cb + 16)*1024 + s*32 + d];
            wc2[s] = Wc[(cb + 32)*1024 + s*32 + d];
            wc3[s] = Wc[(cb + 48)*1024 + s*32 + d];
        }
        u0 = Ux[(cb      )*32 + d];  bb0 = bc[(cb      )*32 + d];
        u1 = Ux[(cb + 16)*32 + d];  bb1 = bc[(cb + 16)*32 + d];
        u2 = Ux[(cb + 32)*32 + d];  bb2 = bc[(cb + 32)*32 + d];
        u3 = Ux[(cb + 48)*32 + d];  bb3 = bc[(cb + 48)*32 + d];
    } else {
        gate_reg = gate0[b*64 + tid];
    }

    // ---------------- time loop: 2 barriers/step ----------------
    for (int t = 0; t < Lsz; ++t) {
        __syncthreads();   // A: new state/err visible; nsT consumed

        if (tid >= 64) {
            // ======== einsum: ns[c][d] = tanh(state@Wc + x*Ux + bc) ========
            const float xt = sm[O_X + t];
            float a0 = bb0 + xt * u0;
            float a1 = bb1 + xt * u1;
            float a2 = bb2 + xt * u2;
            float a3 = bb3 + xt * u3;
            #pragma unroll
            for (int g = 0; g < 8; ++g) {
                const float4 sv = *(const float4*)&sm[O_State + g*4];
                a0 += sv.x*wc0[g*4] + sv.y*wc0[g*4+1] + sv.z*wc0[g*4+2] + sv.w*wc0[g*4+3];
                a1 += sv.x*wc1[g*4] + sv.y*wc1[g*4+1] + sv.z*wc1[g*4+2] + sv.w*wc1[g*4+3];
                a2 += sv.x*wc2[g*4] + sv.y*wc2[g*4+1] + sv.z*wc2[g*4+2] + sv.w*wc2[g*4+3];
                a3 += sv.x*wc3[g*4] + sv.y*wc3[g*4+1] + sv.z*wc3[g*4+2] + sv.w*wc3[g*4+3];
            }
            const int d  = e & 31;
            const int cb = e >> 5;
            sm[O_NsT + d*66 + cb     ] = ftanh(a0);
            sm[O_NsT + d*66 + cb + 16] = ftanh(a1);
            sm[O_NsT + d*66 + cb + 32] = ftanh(a2);
            sm[O_NsT + d*66 + cb + 48] = ftanh(a3);
        } else {
            // ======== wave-0 serial chain ========
            // -- enc --
            {
                const int mr = (tid < 17) ? tid : 0;
                float acc = 0.0f;
                #pragma unroll
                for (int g = 0; g < 8; ++g) {
                    float4 sv = *(const float4*)&sm[O_State + g*4];
                    float4 m  = *(const float4*)&sm[O_Mu + mr*36 + g*4];
                    float dx = sv.x - m.x, dy = sv.y - m.y,
                          dz = sv.z - m.z, dw = sv.w - m.w;
                    acc += dx*dx + dy*dy + dz*dz + dw*dw;
                }
                if (tid < 17) sm[O_Inp + tid] = __expf(-0.5f * acc);
                if (tid == 17) sm[O_Inp + 17] = sm[O_Err];
            }
            WFENCE();
            // -- z1 = inp@Wx1 + h1@Wh1 + b1 --
            float a0 = sm[O_B1 + tid];
            float a1 = sm[O_B1 + 64 + tid];
            #pragma unroll
            for (int g = 0; g < 5; ++g) {      // packed [128][20]
                float4 xv = *(const float4*)&sm[O_Inp + g*4];
                a0 += dot4(xv, *(const float4*)&sm[O_Wx1T + (tid     )*20 + g*4]);
                a1 += dot4(xv, *(const float4*)&sm[O_Wx1T + (tid + 64)*20 + g*4]);
            }
            #pragma unroll
            for (int g = 0; g < 8; ++g) {
                float4 hv = *(const float4*)&sm[O_H1 + g*4];
                a0 += dot4(hv, ldsw(sm + O_Wh1T, tid,      g, 32));
                a1 += dot4(hv, ldsw(sm + O_Wh1T, tid + 64, g, 32));
            }
            {
                float zf = __shfl(a0, tid + 32);
                float zo = __shfl(a1, tid + 32);
                if (tid < 32) {
                    c1 = sigf(zf) * c1 + sigf(a0) * ftanh(a1);
                    sm[O_H1 + tid] = sigf(zo) * ftanh(c1);
                }
            }
            WFENCE();
            // -- z2 = h1@Wx2 + h2@Wh2 + b2 --
            a0 = sm[O_B2 + tid];
            a1 = sm[O_B2 + 64 + tid];
            #pragma unroll
            for (int g = 0; g < 8; ++g) {
                float4 hv = *(const float4*)&sm[O_H1 + g*4];
                a0 += dot4(hv, ldsw(sm + O_Wx2T, tid,      g, 32));
                a1 += dot4(hv, ldsw(sm + O_Wx2T, tid + 64, g, 32));
            }
            #pragma unroll
            for (int g = 0; g < 8; ++g) {
                float4 hv = *(const float4*)&sm[O_H2 + g*4];
                a0 += dot4(hv, ldsw(sm + O_Wh2T, tid,      g, 32));
                a1 += dot4(hv, ldsw(sm + O_Wh2T, tid + 64, g, 32));
            }
            {
                float zf = __shfl(a0, tid + 32);
                float zo = __shfl(a1, tid + 32);
                if (tid < 32) {
                    c2 = sigf(zf) * c2 + sigf(a0) * ftanh(a1);
                    sm[O_H2 + tid] = sigf(zo) * ftanh(c2);
                }
            }
            WFENCE();
            // -- co = h2@Wf + bf --
            {
                const int r = tid & 31;
                float a = sm[O_Bf + r];
                #pragma unroll
                for (int g = 0; g < 8; ++g) {
                    float4 hv = *(const float4*)&sm[O_H2 + g*4];
                    a += dot4(hv, ldsw(sm + O_WfT, r, g, 32));
                }
                if (tid < 32) sm[O_Co + tid] = a;
            }
            WFENCE();
            // -- d1 = relu(co[:31]@Wd1 + bd1) --
            {
                float a = sm[O_Bd1 + tid];
                #pragma unroll
                for (int g = 0; g < 8; ++g) {
                    float4 cv = *(const float4*)&sm[O_Co + g*4];
                    a += dot4(cv, ldsw(sm + O_Wd1T, tid, g, 32));
                }
                sm[O_D1 + tid] = fmaxf(a, 0.0f);
            }
            WFENCE();
            // -- logits + softmax(64) + gate update --
            {
                float a = sm[O_Bd2 + tid];
                #pragma unroll
                for (int g = 0; g < 16; ++g) {
                    float4 dv = *(const float4*)&sm[O_D1 + g*4];
                    a += dot4(dv, ldsw(sm + O_Wd2T, tid, g, 64));
                }
                float mx = a;
                #pragma unroll
                for (int o = 32; o >= 1; o >>= 1) mx = fmaxf(mx, __shfl_xor(mx, o));
                float ex = __expf(a - mx);
                float ssum = ex;
                #pragma unroll
                for (int o = 32; o >= 1; o >>= 1) ssum += __shfl_xor(ssum, o);
                float g = ex / ssum;
                float th = sigf(sm[O_Co + 31]);
                gate_reg = g * th + gate_reg * (1.0f - th);
                sm[O_Gate + tid] = gate_reg;
            }
        }

        __syncthreads();   // B: nsT + gate ready

        if (tid < 64) {
            // ======== P8: state = gate @ ns ; pred ; err ========
            const int row = tid & 31;
            float acc = 0.0f;
            #pragma unroll
            for (int g = 0; g < 16; ++g) {
                float4 gv = *(const float4*)&sm[O_Gate + g*4];
                float2 n0 = *(const float2*)&sm[O_NsT + row*66 + g*4];
                float2 n1 = *(const float2*)&sm[O_NsT + row*66 + g*4 + 2];
                acc += gv.x*n0.x + gv.y*n0.y + gv.z*n1.x + gv.w*n1.y;
            }
            if (tid < 32) {
                sm[O_State + tid] = acc;
                if (tid == 31) {
                    float p = fminf(fmaxf(acc, 0.0f), 1.0f);
                    sm[O_Pred + t] = p;
                    sm[O_Err] = p - sm[O_Y + t];
                }
            }
        }
    }

    // ---------------- epilogue: flush preds ----------------
    __syncthreads();
    for (int i = tid; i < Lsz; i += NT) out[b*Lsz + i] = sm[O_Pred + i];
}

extern "C" void kernel_launch(void* const* d_in, const int* in_sizes, int n_in,
                              void* d_out, int out_size, void* d_ws, size_t ws_size,
                              hipStream_t stream) {
    const float* x    = (const float*)d_in[0];
    const float* y    = (const float*)d_in[1];
    const float* s0   = (const float*)d_in[2];
    const float* err0 = (const float*)d_in[3];
    const float* g0   = (const float*)d_in[4];
    const float* Wc   = (const float*)d_in[5];
    const float* Ux   = (const float*)d_in[6];
    const float* bc   = (const float*)d_in[7];
    const float* mu   = (const float*)d_in[8];
    const float* Wx1  = (const float*)d_in[9];
    const float* Wh1  = (const float*)d_in[10];
    const float* b1   = (const float*)d_in[11];
    const float* Wx2  = (const float*)d_in[12];
    const float* Wh2  = (const float*)d_in[13];
    const float* b2   = (const float*)d_in[14];
    const float* Wo   = (const float*)d_in[15];
    const float* bo   = (const float*)d_in[16];
    const float* Wlin = (const float*)d_in[17];
    const float* blin = (const float*)d_in[18];
    const float* Wd1  = (const float*)d_in[19];
    const float* bd1  = (const float*)d_in[20];
    const float* Wd2  = (const float*)d_in[21];
    const float* bd2  = (const float*)d_in[22];
    float* out = (float*)d_out;

    static bool attr_set = false;
    if (!attr_set) {
        hipFuncSetAttribute((const void*)dnc_kernel,
                            hipFuncAttributeMaxDynamicSharedMemorySize,
                            SMEM_FLOATS * sizeof(float));
        attr_set = true;
    }

    hipLaunchKernelGGL(dnc_kernel, dim3(Bsz), dim3(NT),
                       SMEM_FLOATS * sizeof(float), stream,
                       x, y, s0, err0, g0, Wc, Ux, bc, mu,
                       Wx1, Wh1, b1, Wx2, Wh2, b2,
                       Wo, bo, Wlin, blin, Wd1, bd1, Wd2, bd2, out);
}

// Round 12
// 15675.374 us; speedup vs baseline: 1.0050x; 1.0050x over previous
//
#include <hip/hip_runtime.h>
#include <math.h>

#define Bsz 32
#define Lsz 2048
#define NT  576   // 9 waves: wave 0 = serial chain, waves 1..8 = einsum (512 thr x 4 outputs)

// ---------------- LDS layout (float offsets) ----------------
#define O_Wx1T  0        // [128][20] = 2560  (cols 0..17 real, 18..19 zero)
#define O_Wh1T  2560     // [128][32] = 4096  (XOR-swizzled rows)
#define O_Wx2T  6656     // [128][32] = 4096
#define O_Wh2T  10752    // [128][32] = 4096
#define O_Wd1T  14848    // [64][32]  = 2048  (col 31 zero)
#define O_Wd2T  16896    // [64][64]  = 4096
#define O_WfT   20992    // [32][32]  = 1024  (Wf = Wo@Wlin, transposed)
#define O_Mu    22016    // [17][36]  = 616
#define O_B1    22632    // 128
#define O_B2    22760    // 128
#define O_Bd1   22888    // 64
#define O_Bd2   22952    // 64
#define O_Bf    23016    // 32  (bo@Wlin + blin)
#define O_NsT   23048    // [32][66] = 2112  (nsT[d][c])
#define O_State 25160    // 32
#define O_H1    25192    // 32
#define O_H2    25224    // 32
#define O_Inp   25256    // 24 (18 used; 18..19 zero)
#define O_Co    25280    // 32
#define O_D1    25312    // 64
#define O_Gate  25376    // 64
#define O_Err   25440    // 4
#define O_X     25444    // 2048
#define O_Y     27492    // 2048
#define O_Pred  29540    // 2048
#define SMEM_FLOATS 31588

// XOR swizzle: row j, element k -> float offset within row
#define SW32(j,k) (((((k) >> 2) ^ ((j) & 7)) << 2) | ((k) & 3))
#define SW64(j,k) (((((k) >> 2) ^ ((j) & 7)) << 2) | ((k) & 3))

// SSA vector type: no alloca -> PromoteAlloca can't demote to scratch.
typedef float f32x32 __attribute__((ext_vector_type(32)));

__device__ __forceinline__ float sigf(float v) {
    return 1.0f / (1.0f + __expf(-v));
}
__device__ __forceinline__ float ftanh(float v) {
    float e = __expf(2.0f * v);
    return 1.0f - 2.0f / (e + 1.0f);
}
__device__ __forceinline__ float dot4(float4 a, float4 b) {
    return a.x*b.x + a.y*b.y + a.z*b.z + a.w*b.w;
}
__device__ __forceinline__ float4 ldsw(const float* p, int row, int g, int W) {
    return *(const float4*)(p + row * W + (((g ^ (row & 7)) << 2)));
}
#define WFENCE() do { __builtin_amdgcn_wave_barrier(); } while (0)

// min 3 waves/EU -> VGPR cap 170; required so all 9 waves co-reside (3/SIMD max).
extern "C" __global__ __launch_bounds__(NT, 3)
void dnc_kernel(const float* __restrict__ x,   const float* __restrict__ y,
                const float* __restrict__ s0,  const float* __restrict__ err0,
                const float* __restrict__ gate0,
                const float* __restrict__ Wc,  const float* __restrict__ Ux,
                const float* __restrict__ bc,  const float* __restrict__ mu,
                const float* __restrict__ Wx1, const float* __restrict__ Wh1,
                const float* __restrict__ b1,
                const float* __restrict__ Wx2, const float* __restrict__ Wh2,
                const float* __restrict__ b2,
                const float* __restrict__ Wo,  const float* __restrict__ bo,
                const float* __restrict__ Wlin,const float* __restrict__ blin,
                const float* __restrict__ Wd1, const float* __restrict__ bd1,
                const float* __restrict__ Wd2, const float* __restrict__ bd2,
                float* __restrict__ out)
{
    extern __shared__ float sm[];
    const int tid = threadIdx.x;
    const int b   = blockIdx.x;

    // ---------------- prologue: stage transposed/swizzled weights ----------------
    for (int i = tid; i < 128*20; i += NT) { int j = i / 20, k = i % 20;
        sm[O_Wx1T + i] = (k < 18) ? Wx1[k*128 + j] : 0.0f; }
    for (int i = tid; i < 4096; i += NT) { int j = i & 127, k = i >> 7;
        sm[O_Wh1T + j*32 + SW32(j,k)] = Wh1[k*128 + j]; }
    for (int i = tid; i < 4096; i += NT) { int j = i & 127, k = i >> 7;
        sm[O_Wx2T + j*32 + SW32(j,k)] = Wx2[k*128 + j]; }
    for (int i = tid; i < 4096; i += NT) { int j = i & 127, k = i >> 7;
        sm[O_Wh2T + j*32 + SW32(j,k)] = Wh2[k*128 + j]; }
    for (int i = tid; i < 2048; i += NT) { int j = i & 63, k = i >> 6;
        sm[O_Wd1T + j*32 + SW32(j,k)] = (k < 31) ? Wd1[k*64 + j] : 0.0f; }
    for (int i = tid; i < 4096; i += NT) { int j = i & 63, k = i >> 6;
        sm[O_Wd2T + j*64 + SW64(j,k)] = Wd2[k*64 + j]; }
    for (int i = tid; i < 1024; i += NT) { int j = i & 31, k = i >> 5;
        float a = 0.0f;
        for (int m = 0; m < 18; ++m) a += Wo[k*18 + m] * Wlin[m*32 + j];
        sm[O_WfT + j*32 + SW32(j,k)] = a; }
    for (int i = tid; i < 17*32; i += NT) { int r = i >> 5, s2 = i & 31;
        sm[O_Mu + r*36 + s2] = mu[i]; }
    if (tid < 128) { sm[O_B1 + tid] = b1[tid]; sm[O_B2 + tid] = b2[tid]; }
    if (tid < 64)  { sm[O_Bd1 + tid] = bd1[tid]; sm[O_Bd2 + tid] = bd2[tid]; }
    if (tid < 32)  {
        float a = blin[tid];
        for (int m = 0; m < 18; ++m) a += bo[m] * Wlin[m*32 + tid];
        sm[O_Bf + tid] = a;
        sm[O_State + tid] = s0[tid];
        sm[O_H1 + tid] = 0.0f; sm[O_H2 + tid] = 0.0f;
    }
    if (tid >= 18 && tid < 24) sm[O_Inp + tid] = 0.0f;
    if (tid == 0) sm[O_Err] = err0[b];
    for (int i = tid; i < Lsz; i += NT) sm[O_X + i] = x[b*Lsz + i];
    for (int i = tid; i < Lsz; i += NT) sm[O_Y + i] = y[b*Lsz + i];

    // ---------------- per-thread register state ----------------
    // einsum threads (tid>=64): e in [0,512), outputs o = e + 512k, k=0..3
    //   d = e&31 (same for all k), c = (e>>5) + 16k
    // Init is UNCONDITIONAL (clamped indices) so the SSA vectors are
    // defined on all paths with no divergent phi weirdness.
    const int e  = (tid >= 64) ? (tid - 64) : 0;
    const int d  = e & 31;
    const int cb = e >> 5;

    f32x32 wc0, wc1, wc2, wc3;
    #pragma unroll
    for (int s = 0; s < 32; ++s) {
        wc0[s] = Wc[(cb      )*1024 + s*32 + d];
        wc1[s] = Wc[(cb + 16)*1024 + s*32 + d];
        wc2[s] = Wc[(cb + 32)*1024 + s*32 + d];
        wc3[s] = Wc[(cb + 48)*1024 + s*32 + d];
    }
    const float u0 = Ux[(cb      )*32 + d], bb0 = bc[(cb      )*32 + d];
    const float u1 = Ux[(cb + 16)*32 + d], bb1 = bc[(cb + 16)*32 + d];
    const float u2 = Ux[(cb + 32)*32 + d], bb2 = bc[(cb + 32)*32 + d];
    const float u3 = Ux[(cb + 48)*32 + d], bb3 = bc[(cb + 48)*32 + d];

    float c1 = 0.0f, c2 = 0.0f;
    float gate_reg = gate0[b*64 + (tid & 63)];   // meaningful only for tid<64

    // ---------------- time loop: 2 barriers/step ----------------
    for (int t = 0; t < Lsz; ++t) {
        __syncthreads();   // A: new state/err visible; nsT consumed

        if (tid >= 64) {
            // ======== einsum: ns[c][d] = tanh(state@Wc + x*Ux + bc) ========
            const float xt = sm[O_X + t];
            float a0 = bb0 + xt * u0;
            float a1 = bb1 + xt * u1;
            float a2 = bb2 + xt * u2;
            float a3 = bb3 + xt * u3;
            #pragma unroll
            for (int g = 0; g < 8; ++g) {
                const float4 sv = *(const float4*)&sm[O_State + g*4];
                a0 += sv.x*wc0[g*4] + sv.y*wc0[g*4+1] + sv.z*wc0[g*4+2] + sv.w*wc0[g*4+3];
                a1 += sv.x*wc1[g*4] + sv.y*wc1[g*4+1] + sv.z*wc1[g*4+2] + sv.w*wc1[g*4+3];
                a2 += sv.x*wc2[g*4] + sv.y*wc2[g*4+1] + sv.z*wc2[g*4+2] + sv.w*wc2[g*4+3];
                a3 += sv.x*wc3[g*4] + sv.y*wc3[g*4+1] + sv.z*wc3[g*4+2] + sv.w*wc3[g*4+3];
            }
            sm[O_NsT + d*66 + cb     ] = ftanh(a0);
            sm[O_NsT + d*66 + cb + 16] = ftanh(a1);
            sm[O_NsT + d*66 + cb + 32] = ftanh(a2);
            sm[O_NsT + d*66 + cb + 48] = ftanh(a3);
        } else {
            // ======== wave-0 serial chain ========
            // -- enc --
            {
                const int mr = (tid < 17) ? tid : 0;
                float acc = 0.0f;
                #pragma unroll
                for (int g = 0; g < 8; ++g) {
                    float4 sv = *(const float4*)&sm[O_State + g*4];
                    float4 m  = *(const float4*)&sm[O_Mu + mr*36 + g*4];
                    float dx = sv.x - m.x, dy = sv.y - m.y,
                          dz = sv.z - m.z, dw = sv.w - m.w;
                    acc += dx*dx + dy*dy + dz*dz + dw*dw;
                }
                if (tid < 17) sm[O_Inp + tid] = __expf(-0.5f * acc);
                if (tid == 17) sm[O_Inp + 17] = sm[O_Err];
            }
            WFENCE();
            // -- z1 = inp@Wx1 + h1@Wh1 + b1 --
            float a0 = sm[O_B1 + tid];
            float a1 = sm[O_B1 + 64 + tid];
            #pragma unroll
            for (int g = 0; g < 5; ++g) {      // packed [128][20]
                float4 xv = *(const float4*)&sm[O_Inp + g*4];
                a0 += dot4(xv, *(const float4*)&sm[O_Wx1T + (tid     )*20 + g*4]);
                a1 += dot4(xv, *(const float4*)&sm[O_Wx1T + (tid + 64)*20 + g*4]);
            }
            #pragma unroll
            for (int g = 0; g < 8; ++g) {
                float4 hv = *(const float4*)&sm[O_H1 + g*4];
                a0 += dot4(hv, ldsw(sm + O_Wh1T, tid,      g, 32));
                a1 += dot4(hv, ldsw(sm + O_Wh1T, tid + 64, g, 32));
            }
            {
                float zf = __shfl(a0, tid + 32);
                float zo = __shfl(a1, tid + 32);
                if (tid < 32) {
                    c1 = sigf(zf) * c1 + sigf(a0) * ftanh(a1);
                    sm[O_H1 + tid] = sigf(zo) * ftanh(c1);
                }
            }
            WFENCE();
            // -- z2 = h1@Wx2 + h2@Wh2 + b2 --
            a0 = sm[O_B2 + tid];
            a1 = sm[O_B2 + 64 + tid];
            #pragma unroll
            for (int g = 0; g < 8; ++g) {
                float4 hv = *(const float4*)&sm[O_H1 + g*4];
                a0 += dot4(hv, ldsw(sm + O_Wx2T, tid,      g, 32));
                a1 += dot4(hv, ldsw(sm + O_Wx2T, tid + 64, g, 32));
            }
            #pragma unroll
            for (int g = 0; g < 8; ++g) {
                float4 hv = *(const float4*)&sm[O_H2 + g*4];
                a0 += dot4(hv, ldsw(sm + O_Wh2T, tid,      g, 32));
                a1 += dot4(hv, ldsw(sm + O_Wh2T, tid + 64, g, 32));
            }
            {
                float zf = __shfl(a0, tid + 32);
                float zo = __shfl(a1, tid + 32);
                if (tid < 32) {
                    c2 = sigf(zf) * c2 + sigf(a0) * ftanh(a1);
                    sm[O_H2 + tid] = sigf(zo) * ftanh(c2);
                }
            }
            WFENCE();
            // -- co = h2@Wf + bf --
            {
                const int r = tid & 31;
                float a = sm[O_Bf + r];
                #pragma unroll
                for (int g = 0; g < 8; ++g) {
                    float4 hv = *(const float4*)&sm[O_H2 + g*4];
                    a += dot4(hv, ldsw(sm + O_WfT, r, g, 32));
                }
                if (tid < 32) sm[O_Co + tid] = a;
            }
            WFENCE();
            // -- d1 = relu(co[:31]@Wd1 + bd1) --
            {
                float a = sm[O_Bd1 + tid];
                #pragma unroll
                for (int g = 0; g < 8; ++g) {
                    float4 cv = *(const float4*)&sm[O_Co + g*4];
                    a += dot4(cv, ldsw(sm + O_Wd1T, tid, g, 32));
                }
                sm[O_D1 + tid] = fmaxf(a, 0.0f);
            }
            WFENCE();
            // -- logits + softmax(64) + gate update --
            {
                float a = sm[O_Bd2 + tid];
                #pragma unroll
                for (int g = 0; g < 16; ++g) {
                    float4 dv = *(const float4*)&sm[O_D1 + g*4];
                    a += dot4(dv, ldsw(sm + O_Wd2T, tid, g, 64));
                }
                float mx = a;
                #pragma unroll
                for (int o = 32; o >= 1; o >>= 1) mx = fmaxf(mx, __shfl_xor(mx, o));
                float ex = __expf(a - mx);
                float ssum = ex;
                #pragma unroll
                for (int o = 32; o >= 1; o >>= 1) ssum += __shfl_xor(ssum, o);
                float g = ex / ssum;
                float th = sigf(sm[O_Co + 31]);
                gate_reg = g * th + gate_reg * (1.0f - th);
                sm[O_Gate + tid] = gate_reg;
            }
        }

        __syncthreads();   // B: nsT + gate ready

        if (tid < 64) {
            // ======== P8: state = gate @ ns ; pred ; err ========
            const int row = tid & 31;
            float acc = 0.0f;
            #pragma unroll
            for (int g = 0; g < 16; ++g) {
                float4 gv = *(const float4*)&sm[O_Gate + g*4];
                float2 n0 = *(const float2*)&sm[O_NsT + row*66 + g*4];
                float2 n1 = *(const float2*)&sm[O_NsT + row*66 + g*4 + 2];
                acc += gv.x*n0.x + gv.y*n0.y + gv.z*n1.x + gv.w*n1.y;
            }
            if (tid < 32) {
                sm[O_State + tid] = acc;
                if (tid == 31) {
                    float p = fminf(fmaxf(acc, 0.0f), 1.0f);
                    sm[O_Pred + t] = p;
                    sm[O_Err] = p - sm[O_Y + t];
                }
            }
        }
    }

    // ---------------- epilogue: flush preds ----------------
    __syncthreads();
    for (int i = tid; i < Lsz; i += NT) out[b*Lsz + i] = sm[O_Pred + i];
}

extern "C" void kernel_launch(void* const* d_in, const int* in_sizes, int n_in,
                              void* d_out, int out_size, void* d_ws, size_t ws_size,
                              hipStream_t stream) {
    const float* x    = (const float*)d_in[0];
    const float* y    = (const float*)d_in[1];
    const float* s0   = (const float*)d_in[2];
    const float* err0 = (const float*)d_in[3];
    const float* g0   = (const float*)d_in[4];
    const float* Wc   = (const float*)d_in[5];
    const float* Ux   = (const float*)d_in[6];
    const float* bc   = (const float*)d_in[7];
    const float* mu   = (const float*)d_in[8];
    const float* Wx1  = (const float*)d_in[9];
    const float* Wh1  = (const float*)d_in[10];
    const float* b1   = (const float*)d_in[11];
    const float* Wx2  = (const float*)d_in[12];
    const float* Wh2  = (const float*)d_in[13];
    const float* b2   = (const float*)d_in[14];
    const float* Wo   = (const float*)d_in[15];
    const float* bo   = (const float*)d_in[16];
    const float* Wlin = (const float*)d_in[17];
    const float* blin = (const float*)d_in[18];
    const float* Wd1  = (const float*)d_in[19];
    const float* bd1  = (const float*)d_in[20];
    const float* Wd2  = (const float*)d_in[21];
    const float* bd2  = (const float*)d_in[22];
    float* out = (float*)d_out;

    static bool attr_set = false;
    if (!attr_set) {
        hipFuncSetAttribute((const void*)dnc_kernel,
                            hipFuncAttributeMaxDynamicSharedMemorySize,
                            SMEM_FLOATS * sizeof(float));
        attr_set = true;
    }

    hipLaunchKernelGGL(dnc_kernel, dim3(Bsz), dim3(NT),
                       SMEM_FLOATS * sizeof(float), stream,
                       x, y, s0, err0, g0, Wc, Ux, bc, mu,
                       Wx1, Wh1, b1, Wx2, Wh2, b2,
                       Wo, bo, Wlin, blin, Wd1, bd1, Wd2, bd2, out);
}